// Round 1
// baseline (66.600 us; speedup 1.0000x reference)
//
#include <hip/hip_runtime.h>
#include <hip/hip_bf16.h>
#include <stdint.h>

// NT-Xent loss, B=4096, D=256, T=0.5, eps=1e-8.
// loss_r = log(sum_{c!=r} exp(2*dot(zn_r,zn_c))) - 2*dot(zin_r, zjn_r); out = mean.

#define BROWS 4096
#define DIM   256
#define N2    8192

typedef __attribute__((ext_vector_type(4))) float  f32x4;
typedef __attribute__((ext_vector_type(8))) short  s16x8;

__device__ inline unsigned short f2bf(float f) {
    uint32_t b = __float_as_uint(f);
    b += 0x7fffu + ((b >> 16) & 1u);   // RNE
    return (unsigned short)(b >> 16);
}

__device__ inline void gload_lds16(const void* g, void* l) {
    __builtin_amdgcn_global_load_lds(
        (const __attribute__((address_space(1))) uint32_t*)g,
        (__attribute__((address_space(3))) uint32_t*)l, 16, 0, 0);
}

// ---- K1: normalize rows of concat(z_i, z_j) -> bf16 zn[8192][256], save scale ----
__global__ __launch_bounds__(256) void k_normalize(const float* __restrict__ zi,
                                                   const float* __restrict__ zj,
                                                   unsigned short* __restrict__ zn,
                                                   float* __restrict__ rnorm) {
    int row  = blockIdx.x * 4 + (threadIdx.x >> 6);
    int lane = threadIdx.x & 63;
    const float* src = (row < BROWS) ? (zi + (size_t)row * DIM)
                                     : (zj + (size_t)(row - BROWS) * DIM);
    f32x4 v = *(const f32x4*)(src + lane * 4);
    float ss = v[0]*v[0] + v[1]*v[1] + v[2]*v[2] + v[3]*v[3];
    #pragma unroll
    for (int m = 1; m < 64; m <<= 1) ss += __shfl_xor(ss, m);
    float scale = 1.0f / fmaxf(sqrtf(ss), 1e-8f);
    if (lane == 0) rnorm[row] = scale;
    unsigned short o0 = f2bf(v[0]*scale), o1 = f2bf(v[1]*scale);
    unsigned short o2 = f2bf(v[2]*scale), o3 = f2bf(v[3]*scale);
    typedef __attribute__((ext_vector_type(4))) unsigned short u16x4;
    u16x4 o = { o0, o1, o2, o3 };
    *(u16x4*)(zn + (size_t)row * DIM + lane * 4) = o;
}

// ---- K2: positive-pair similarity (fp32, matches reference path) ----
__global__ __launch_bounds__(256) void k_pos(const float* __restrict__ zi,
                                             const float* __restrict__ zj,
                                             const float* __restrict__ rnorm,
                                             float* __restrict__ pos_sim) {
    int i    = blockIdx.x * 4 + (threadIdx.x >> 6);
    int lane = threadIdx.x & 63;
    f32x4 a = *(const f32x4*)(zi + (size_t)i * DIM + lane * 4);
    f32x4 b = *(const f32x4*)(zj + (size_t)i * DIM + lane * 4);
    float d = a[0]*b[0] + a[1]*b[1] + a[2]*b[2] + a[3]*b[3];
    #pragma unroll
    for (int m = 1; m < 64; m <<= 1) d += __shfl_xor(d, m);
    if (lane == 0) pos_sim[i] = 2.0f * d * rnorm[i] * rnorm[i + BROWS];
}

// ---- K3: fused sim GEMM + exp + row-sum (diagonal masked) ----
// Block: 256 thr = 4 waves; 256 rows x 512 cols per block; grid = 32*16 = 512.
// Wave owns 64 rows (4 row-tiles of 16), A-frags in registers (K=256).
// B staged in LDS 64 cols x 256 K, K-major subtiled: byte = kc*4096 + g*1024 + c*16.
__global__ __launch_bounds__(256, 2) void k_simsum(const unsigned short* __restrict__ zn,
                                                   float* __restrict__ partial) {
    __shared__ unsigned short lds[64 * DIM];   // 32 KB
    int bid = blockIdx.x;
    int rb = bid & 31;        // 32 row-blocks of 256
    int cc = bid >> 5;        // 16 col-chunks of 512
    int rowbase = rb * 256;
    int colbase = cc * 512;
    int tid = threadIdx.x, lane = tid & 63, w = tid >> 6;
    int cl = lane & 15, g = lane >> 4;

    // A fragments: lane holds zn[row0 + cl][kc*32 + g*8 .. +8]
    s16x8 afrag[4][8];
    #pragma unroll
    for (int rt = 0; rt < 4; ++rt) {
        int row = rowbase + w * 64 + rt * 16 + cl;
        const unsigned short* ap = zn + (size_t)row * DIM + g * 8;
        #pragma unroll
        for (int kc = 0; kc < 8; ++kc)
            afrag[rt][kc] = *(const s16x8*)(ap + kc * 32);
    }

    float pp[4][4];
    #pragma unroll
    for (int rt = 0; rt < 4; ++rt)
        #pragma unroll
        for (int r = 0; r < 4; ++r) pp[rt][r] = 0.0f;

    const float K_EXP = 2.8853900817779268f;  // 2 * log2(e)  (== log2e / T)

    for (int s = 0; s < 8; ++s) {
        __syncthreads();   // previous tile's reads done
        {
            int crow = colbase + s * 64 + lane;            // zn row being staged
            const unsigned short* gsrc = zn + (size_t)crow * DIM;
            #pragma unroll
            for (int i = 0; i < 8; ++i) {
                // LDS dest (wave-uniform base): i*4096 + w*1024 ; HW adds lane*16
                // content: zn[crow][i*32 + w*8 .. +8]
                gload_lds16(gsrc + i * 32 + w * 8,
                            (char*)lds + i * 4096 + w * 1024);
            }
        }
        __syncthreads();   // staging complete

        #pragma unroll
        for (int ct = 0; ct < 4; ++ct) {
            f32x4 acc[4];
            #pragma unroll
            for (int rt = 0; rt < 4; ++rt) acc[rt] = (f32x4){0.f, 0.f, 0.f, 0.f};
            #pragma unroll
            for (int kc = 0; kc < 8; ++kc) {
                s16x8 bfrag = *(const s16x8*)((const char*)lds +
                                 kc * 4096 + g * 1024 + (ct * 16 + cl) * 16);
                #pragma unroll
                for (int rt = 0; rt < 4; ++rt)
                    acc[rt] = __builtin_amdgcn_mfma_f32_16x16x32_bf16(
                                  afrag[rt][kc], bfrag, acc[rt], 0, 0, 0);
            }
            int gcol = colbase + s * 64 + ct * 16 + cl;
            #pragma unroll
            for (int rt = 0; rt < 4; ++rt) {
                int grow0 = rowbase + w * 64 + rt * 16 + g * 4;
                #pragma unroll
                for (int r = 0; r < 4; ++r) {
                    float e = __builtin_amdgcn_exp2f(acc[rt][r] * K_EXP);
                    pp[rt][r] += (grow0 + r != gcol) ? e : 0.0f;
                }
            }
        }
    }

    // reduce across the 16 col-lanes (cl) within each g-group
    #pragma unroll
    for (int rt = 0; rt < 4; ++rt) {
        #pragma unroll
        for (int r = 0; r < 4; ++r) {
            float v = pp[rt][r];
            v += __shfl_xor(v, 1);
            v += __shfl_xor(v, 2);
            v += __shfl_xor(v, 4);
            v += __shfl_xor(v, 8);
            if (cl == 0)
                partial[(size_t)cc * N2 + rowbase + w * 64 + rt * 16 + g * 4 + r] = v;
        }
    }
}

// ---- K4: final reduce: mean over rows of log(rowsum) - pos_sim ----
__global__ __launch_bounds__(256) void k_final(const float* __restrict__ partial,
                                               const float* __restrict__ pos_sim,
                                               float* __restrict__ out) {
    int tid = threadIdx.x;
    float local = 0.0f;
    for (int r = tid; r < N2; r += 256) {
        float sum = 0.0f;
        #pragma unroll
        for (int c = 0; c < 16; ++c) sum += partial[(size_t)c * N2 + r];
        local += __builtin_amdgcn_logf(sum) * 0.6931471805599453f - pos_sim[r & (BROWS - 1)];
    }
    #pragma unroll
    for (int m = 1; m < 64; m <<= 1) local += __shfl_xor(local, m);
    __shared__ float red[4];
    if ((tid & 63) == 0) red[tid >> 6] = local;
    __syncthreads();
    if (tid == 0) out[0] = (red[0] + red[1] + red[2] + red[3]) * (1.0f / N2);
}

extern "C" void kernel_launch(void* const* d_in, const int* in_sizes, int n_in,
                              void* d_out, int out_size, void* d_ws, size_t ws_size,
                              hipStream_t stream) {
    const float* zi = (const float*)d_in[0];
    const float* zj = (const float*)d_in[1];
    float* out = (float*)d_out;

    char* ws = (char*)d_ws;
    unsigned short* zn  = (unsigned short*)ws;                      // 4 MB
    float* rnorm        = (float*)(ws + (4u << 20));                // 32 KB
    float* pos_sim      = (float*)(ws + (4u << 20) + (32u << 10));  // 16 KB
    float* partial      = (float*)(ws + (4u << 20) + (48u << 10));  // 512 KB

    k_normalize<<<N2 / 4, 256, 0, stream>>>(zi, zj, zn, rnorm);
    k_pos<<<BROWS / 4, 256, 0, stream>>>(zi, zj, rnorm, pos_sim);
    k_simsum<<<512, 256, 0, stream>>>(zn, partial);
    k_final<<<1, 256, 0, stream>>>(partial, pos_sim, out);
}